// Round 7
// baseline (233.179 us; speedup 1.0000x reference)
//
#include <hip/hip_runtime.h>
#include <hip/hip_fp16.h>
#include <math.h>

// Problem constants
#define HID   1024
#define NHEAD 16
#define HD    64
#define NB    64
#define MAXS  2048
#define CHUNK 256
#define NCH   (MAXS / CHUNK)          // 8
#define PS    68                      // floats per (chunk,b,h) partial record

// Non-temporal float4 load (sets the nt cache bit: stream-once data,
// don't retain in L1/L2 — probing the read-path-concurrency theory).
typedef float f4v __attribute__((ext_vector_type(4)));
__device__ __forceinline__ float4 ntload4(const float* p) {
    f4v v = __builtin_nontemporal_load((const f4v*)p);
    return make_float4(v.x, v.y, v.z, v.w);
}

// ---------------------------------------------------------------------------
// Kernel 1: fused projections (unchanged — W read exactly once)
// ---------------------------------------------------------------------------
__global__ __launch_bounds__(1024) void proj_kernel(
    const float* __restrict__ seq, const float* __restrict__ cand,
    const float* __restrict__ Wqkv, const float* __restrict__ bqkv,
    const float* __restrict__ Wc,   const float* __restrict__ bcv,
    float* __restrict__ out /* [4096][64] col-major */)
{
    const int tid  = threadIdx.x;
    const int wv   = __builtin_amdgcn_readfirstlane(tid >> 6);
    const int lane = tid & 63;
    const int c0   = blockIdx.x * 16;
    const bool is_qkv = (c0 < 3072);
    const float* __restrict__ src  = is_qkv ? seq  : cand;
    const float* __restrict__ W    = is_qkv ? Wqkv : Wc;
    const float* __restrict__ bias = is_qkv ? bqkv : bcv;
    const int ldw = is_qkv ? 3072 : 1024;
    const int cb  = is_qkv ? c0 : (c0 - 3072);
    const int k0  = wv * 64;

    float acc[16];
    #pragma unroll
    for (int j = 0; j < 16; ++j) acc[j] = 0.f;

    const float4* sp = (const float4*)(src + lane * HID + k0);
    for (int kc = 0; kc < 16; ++kc) {
        float4 s4 = sp[kc];
        const float* wb = W + (size_t)(k0 + kc * 4) * ldw + cb;
        #pragma unroll
        for (int t = 0; t < 4; ++t) {
            float sv = (t == 0) ? s4.x : (t == 1) ? s4.y : (t == 2) ? s4.z : s4.w;
            const float4* wr = (const float4*)(wb + (size_t)t * ldw);
            #pragma unroll
            for (int j = 0; j < 4; ++j) {
                float4 w4 = wr[j];
                acc[4*j+0] = fmaf(sv, w4.x, acc[4*j+0]);
                acc[4*j+1] = fmaf(sv, w4.y, acc[4*j+1]);
                acc[4*j+2] = fmaf(sv, w4.z, acc[4*j+2]);
                acc[4*j+3] = fmaf(sv, w4.w, acc[4*j+3]);
            }
        }
    }

    __shared__ float red[16][16][64];
    #pragma unroll
    for (int j = 0; j < 16; ++j) red[wv][j][lane] = acc[j];
    __syncthreads();

    {
        const int j = tid >> 6, b = tid & 63;
        float s = 0.f;
        #pragma unroll
        for (int w = 0; w < 16; ++w) s += red[w][j][b];
        out[(c0 + j) * 64 + b] = s + bias[cb + j];
    }
}

// ---------------------------------------------------------------------------
// Kernel 2a: TWO-PHASE chunked attention partials (R5 structure) with
// NON-TEMPORAL k/v loads. Block (c,b,h): 16 groups x 16 lanes.
// ---------------------------------------------------------------------------
__global__ __launch_bounds__(256) void attn_part_kernel(
    const float* __restrict__ proj, const float* __restrict__ k_cache,
    const float* __restrict__ v_cache, const int* __restrict__ seqlens,
    float* __restrict__ part)
{
    const int idx = blockIdx.x;
    const int c  = idx >> 10;          // chunk slowest: early blocks all valid
    const int bh = idx & 1023;
    const int b  = bh >> 4;
    const int h  = bh & 15;
    const int L  = seqlens[b];
    const int s0 = c << 8;
    if (s0 > L) return;

    const int tid = threadIdx.x;
    const int grp = tid >> 4;
    const int gl  = tid & 15;
    const bool has_new = (L < s0 + CHUNK);

    __shared__ float lq[64], lk[64], lv[64];
    __shared__ float sm_m[16], sm_l[16];
    __shared__ float sm_o[16][64];

    if (tid < 64) {                    // wave 0: q
        lq[tid] = proj[(h * 192 + tid) * 64 + b];
    } else if (tid < 128) {            // wave 1: normalized + fp16-rounded new k
        if (has_new) {
            int d = tid - 64;
            float kr = proj[(h * 192 + 64 + d) * 64 + b];
            float ss = kr * kr;
            #pragma unroll
            for (int m = 1; m < 64; m <<= 1) ss += __shfl_xor(ss, m);
            float kn = kr / sqrtf(ss);
            lk[d] = __half2float(__float2half_rn(kn));
        }
    } else if (tid < 192) {            // wave 2: new v
        if (has_new) {
            int d = tid - 128;
            lv[d] = proj[(h * 192 + 128 + d) * 64 + b];
        }
    }
    __syncthreads();

    const float4 q4 = ((const float4*)lq)[gl];
    const size_t base0 = (((size_t)b * MAXS) * NHEAD + h) * HD;

    float sc[16];
    float m, l;
    float4 o = make_float4(0.f, 0.f, 0.f, 0.f);

    if (!has_new) {
        // ---- Phase 1: K stream (nt), 16 independent score computations ----
        #pragma unroll
        for (int t = 0; t < 16; ++t) {
            const int s = s0 + grp + t * 16;
            float4 k4 = ntload4(k_cache + base0 + (size_t)s * (NHEAD * HD) + gl * 4);
            float d = fmaf(k4.x, q4.x, fmaf(k4.y, q4.y, fmaf(k4.z, q4.z, k4.w * q4.w)));
            d += __shfl_xor(d, 1); d += __shfl_xor(d, 2);
            d += __shfl_xor(d, 4); d += __shfl_xor(d, 8);
            sc[t] = d;
        }
        // ---- in-register softmax over the 16 scores ----
        m = sc[0];
        #pragma unroll
        for (int t = 1; t < 16; ++t) m = fmaxf(m, sc[t]);
        l = 0.f;
        #pragma unroll
        for (int t = 0; t < 16; ++t) { float p = __expf(sc[t] - m); sc[t] = p; l += p; }
        // ---- Phase 2: V stream (nt), independent accumulation ----
        #pragma unroll
        for (int t = 0; t < 16; ++t) {
            const int s = s0 + grp + t * 16;
            float4 v4 = ntload4(v_cache + base0 + (size_t)s * (NHEAD * HD) + gl * 4);
            o.x = fmaf(sc[t], v4.x, o.x);
            o.y = fmaf(sc[t], v4.y, o.y);
            o.z = fmaf(sc[t], v4.z, o.z);
            o.w = fmaf(sc[t], v4.w, o.w);
        }
    } else {
        // tail chunk: predicated, compile-time trip count
        #pragma unroll
        for (int t = 0; t < 16; ++t) {
            const int s = s0 + grp + t * 16;
            float4 k4 = make_float4(0.f, 0.f, 0.f, 0.f);
            if (s < L)       k4 = ntload4(k_cache + base0 + (size_t)s * (NHEAD * HD) + gl * 4);
            else if (s == L) k4 = ((const float4*)lk)[gl];
            float d = fmaf(k4.x, q4.x, fmaf(k4.y, q4.y, fmaf(k4.z, q4.z, k4.w * q4.w)));
            d += __shfl_xor(d, 1); d += __shfl_xor(d, 2);
            d += __shfl_xor(d, 4); d += __shfl_xor(d, 8);
            sc[t] = (s <= L) ? d : -INFINITY;
        }
        m = sc[0];
        #pragma unroll
        for (int t = 1; t < 16; ++t) m = fmaxf(m, sc[t]);
        // NaN guard: group entirely past L -> m = -inf; subtract 0 so
        // exp(-inf - 0) = 0, l = 0 (merge weight exp(-inf - M) = 0).
        const float mm = (m == -INFINITY) ? 0.f : m;
        l = 0.f;
        #pragma unroll
        for (int t = 0; t < 16; ++t) { float p = __expf(sc[t] - mm); sc[t] = p; l += p; }
        #pragma unroll
        for (int t = 0; t < 16; ++t) {
            const int s = s0 + grp + t * 16;
            float4 v4 = make_float4(0.f, 0.f, 0.f, 0.f);
            if (s < L)       v4 = ntload4(v_cache + base0 + (size_t)s * (NHEAD * HD) + gl * 4);
            else if (s == L) v4 = ((const float4*)lv)[gl];
            o.x = fmaf(sc[t], v4.x, o.x);
            o.y = fmaf(sc[t], v4.y, o.y);
            o.z = fmaf(sc[t], v4.z, o.z);
            o.w = fmaf(sc[t], v4.w, o.w);
        }
    }

    // ---- merge the 16 group-partials ----
    if (gl == 0) { sm_m[grp] = m; sm_l[grp] = l; }
    ((float4*)sm_o[grp])[gl] = o;
    __syncthreads();

    if (tid < 64) {
        float M = -INFINITY;
        #pragma unroll
        for (int g = 0; g < 16; ++g) M = fmaxf(M, sm_m[g]);
        float li = 0.f, oi = 0.f;
        #pragma unroll
        for (int g = 0; g < 16; ++g) {
            float w = __expf(sm_m[g] - M);   // empty group: exp(-inf - M) = 0
            li += w * sm_l[g];
            oi += w * sm_o[g][tid];
        }
        float* pb = part + (size_t)(c * 1024 + bh) * PS;
        pb[tid] = oi;
        if (tid == 0) { pb[64] = M; pb[65] = li; }
    }
}

// ---------------------------------------------------------------------------
// Kernel 2b: merge <=8 chunk partials per (b,h). 1024 blocks x 64 threads.
// ---------------------------------------------------------------------------
__global__ __launch_bounds__(64) void attn_merge_kernel(
    const float* __restrict__ part, const int* __restrict__ seqlens,
    float* __restrict__ attn_out /* [1024][64] col-major */)
{
    const int bh = blockIdx.x;
    const int b  = bh >> 4;
    const int h  = bh & 15;
    const int d  = threadIdx.x;
    const int nch = (seqlens[b] >> 8) + 1;

    float M = -INFINITY, l = 0.f, o = 0.f;
    for (int c = 0; c < nch; ++c) {
        const float* pb = part + (size_t)(c * 1024 + bh) * PS;
        float mc = pb[64], lc = pb[65];
        float Mn = fmaxf(M, mc);
        float f = __expf(M - Mn);
        float w = __expf(mc - Mn);
        o = o * f + w * pb[d];
        l = l * f + w * lc;
        M = Mn;
    }
    attn_out[(h * 64 + d) * 64 + b] = o / l;
}

// ---------------------------------------------------------------------------
// Kernel 3: postx = attn @ Wo + bo (unchanged)
// ---------------------------------------------------------------------------
__global__ __launch_bounds__(1024) void wo_kernel(
    const float* __restrict__ attn_s, const float* __restrict__ Wo,
    const float* __restrict__ bo, float* __restrict__ postx /* [1024][64] */)
{
    const int tid  = threadIdx.x;
    const int wv   = __builtin_amdgcn_readfirstlane(tid >> 6);
    const int lane = tid & 63;
    const int c0   = blockIdx.x * 8;
    const int k0   = wv * 64;

    float acc[8];
    #pragma unroll
    for (int j = 0; j < 8; ++j) acc[j] = 0.f;

    for (int k = 0; k < 64; ++k) {
        float sv = attn_s[(k0 + k) * 64 + lane];
        const float4* wr = (const float4*)(Wo + (size_t)(k0 + k) * 1024 + c0);
        float4 w0 = wr[0], w1 = wr[1];
        acc[0] = fmaf(sv, w0.x, acc[0]); acc[1] = fmaf(sv, w0.y, acc[1]);
        acc[2] = fmaf(sv, w0.z, acc[2]); acc[3] = fmaf(sv, w0.w, acc[3]);
        acc[4] = fmaf(sv, w1.x, acc[4]); acc[5] = fmaf(sv, w1.y, acc[5]);
        acc[6] = fmaf(sv, w1.z, acc[6]); acc[7] = fmaf(sv, w1.w, acc[7]);
    }

    __shared__ float red[16][8][64];
    #pragma unroll
    for (int j = 0; j < 8; ++j) red[wv][j][lane] = acc[j];
    __syncthreads();

    if (tid < 512) {
        const int j = tid >> 6, b = tid & 63;
        float s = 0.f;
        #pragma unroll
        for (int w = 0; w < 16; ++w) s += red[w][j][b];
        postx[(c0 + j) * 64 + b] = s + bo[c0 + j];
    }
}

// ---------------------------------------------------------------------------
// Kernel 4: dual LayerNorm (unchanged)
// ---------------------------------------------------------------------------
__global__ __launch_bounds__(256) void ln_kernel(
    const float* __restrict__ seq, const float* __restrict__ cand_s,
    const float* __restrict__ postx, const float* __restrict__ gamma,
    const float* __restrict__ beta, float* __restrict__ out)
{
    const int b   = blockIdx.x;
    const int tid = threadIdx.x;
    float x1[4], x2[4];
    float s1 = 0.f, q1 = 0.f, s2 = 0.f, q2 = 0.f;

    #pragma unroll
    for (int i = 0; i < 4; ++i) {
        int c = tid + i * 256;
        float px = postx[c * 64 + b];
        float sv = seq[b * HID + c];
        float cd = cand_s[c * 64 + b];
        float a = sv + px, d = px + cd;
        x1[i] = a; x2[i] = d;
        s1 += a; q1 += a * a; s2 += d; q2 += d * d;
    }
    #pragma unroll
    for (int m = 1; m < 64; m <<= 1) {
        s1 += __shfl_xor(s1, m); q1 += __shfl_xor(q1, m);
        s2 += __shfl_xor(s2, m); q2 += __shfl_xor(q2, m);
    }
    __shared__ float rsm[4][4];
    const int wv = tid >> 6, lane = tid & 63;
    if (lane == 0) { rsm[wv][0] = s1; rsm[wv][1] = q1; rsm[wv][2] = s2; rsm[wv][3] = q2; }
    __syncthreads();

    float S1 = rsm[0][0] + rsm[1][0] + rsm[2][0] + rsm[3][0];
    float Q1 = rsm[0][1] + rsm[1][1] + rsm[2][1] + rsm[3][1];
    float S2 = rsm[0][2] + rsm[1][2] + rsm[2][2] + rsm[3][2];
    float Q2 = rsm[0][3] + rsm[1][3] + rsm[2][3] + rsm[3][3];

    const float inv = 1.f / 1024.f;
    float mu1 = S1 * inv, v1 = Q1 * inv - mu1 * mu1;
    float mu2 = S2 * inv, v2 = Q2 * inv - mu2 * mu2;
    float r1 = rsqrtf(v1 + 1e-5f);
    float r2 = rsqrtf(v2 + 1e-5f);

    #pragma unroll
    for (int i = 0; i < 4; ++i) {
        int c = tid + i * 256;
        float g = gamma[c], be = beta[c];
        out[b * HID + c]            = (x1[i] - mu1) * r1 * g + be;   // seq_out
        out[NB * HID + b * HID + c] = (x2[i] - mu2) * r2 * g + be;   // candidate_out
    }
}

// ---------------------------------------------------------------------------
extern "C" void kernel_launch(void* const* d_in, const int* in_sizes, int n_in,
                              void* d_out, int out_size, void* d_ws, size_t ws_size,
                              hipStream_t stream) {
    const float* seq      = (const float*)d_in[0];
    const float* cand     = (const float*)d_in[1];
    const float* k_cache  = (const float*)d_in[2];
    const float* v_cache  = (const float*)d_in[3];
    const int*   seqlens  = (const int*)  d_in[4];
    const float* Wqkv     = (const float*)d_in[5];
    const float* bqkv     = (const float*)d_in[6];
    const float* Wc       = (const float*)d_in[7];
    const float* bcv      = (const float*)d_in[8];
    const float* Wo       = (const float*)d_in[9];
    const float* bo       = (const float*)d_in[10];
    const float* gamma    = (const float*)d_in[11];
    const float* beta     = (const float*)d_in[12];
    float* out = (float*)d_out;

    float* ws    = (float*)d_ws;
    float* proj  = ws;                         // [4096][64] = 262144 f
    float* attn  = proj  + 4096 * 64;          // [1024][64] =  65536 f
    float* postx = attn  + 1024 * 64;          // [1024][64] =  65536 f
    float* part  = postx + 1024 * 64;          // [8*1024][PS] = 557056 f
    float* part2 = part  + NCH * 1024 * PS;    // timing probe scratch (same size)

    proj_kernel      <<<256, 1024, 0, stream>>>(seq, cand, Wqkv, bqkv, Wc, bcv, proj);
    // Launched TWICE (second into scratch): dur = fixed + 2*T_attn lets us
    // split component times exactly. Merge reads the FIRST launch's output.
    attn_part_kernel <<<NCH * 1024, 256, 0, stream>>>(proj, k_cache, v_cache, seqlens, part);
    attn_part_kernel <<<NCH * 1024, 256, 0, stream>>>(proj, k_cache, v_cache, seqlens, part2);
    attn_merge_kernel<<<NB * NHEAD, 64, 0, stream>>>(part, seqlens, attn);
    wo_kernel        <<<128, 1024, 0, stream>>>(attn, Wo, bo, postx);
    ln_kernel        <<<NB, 256, 0, stream>>>(seq, proj + 3072 * 64, postx, gamma, beta, out);
}

// Round 8
// 149.463 us; speedup vs baseline: 1.5601x; 1.5601x over previous
//
#include <hip/hip_runtime.h>
#include <hip/hip_fp16.h>
#include <math.h>

// Problem constants
#define HID   1024
#define NHEAD 16
#define HD    64
#define NB    64
#define MAXS  2048
#define CHUNK 256
#define NCH   (MAXS / CHUNK)          // 8
#define PS    68                      // floats per (chunk,b,h) partial record

// Non-temporal float4 load: skips cache retention on the streamed-once KV
// read. Measured (R5 vs R7 pair): ~3.4 -> ~5.1 TB/s on the KV stream.
typedef float f4v __attribute__((ext_vector_type(4)));
__device__ __forceinline__ float4 ntload4(const float* p) {
    f4v v = __builtin_nontemporal_load((const f4v*)p);
    return make_float4(v.x, v.y, v.z, v.w);
}

// ---------------------------------------------------------------------------
// Kernel 1: fused projections (unchanged — W read exactly once)
// ---------------------------------------------------------------------------
__global__ __launch_bounds__(1024) void proj_kernel(
    const float* __restrict__ seq, const float* __restrict__ cand,
    const float* __restrict__ Wqkv, const float* __restrict__ bqkv,
    const float* __restrict__ Wc,   const float* __restrict__ bcv,
    float* __restrict__ out /* [4096][64] col-major */)
{
    const int tid  = threadIdx.x;
    const int wv   = __builtin_amdgcn_readfirstlane(tid >> 6);
    const int lane = tid & 63;
    const int c0   = blockIdx.x * 16;
    const bool is_qkv = (c0 < 3072);
    const float* __restrict__ src  = is_qkv ? seq  : cand;
    const float* __restrict__ W    = is_qkv ? Wqkv : Wc;
    const float* __restrict__ bias = is_qkv ? bqkv : bcv;
    const int ldw = is_qkv ? 3072 : 1024;
    const int cb  = is_qkv ? c0 : (c0 - 3072);
    const int k0  = wv * 64;

    float acc[16];
    #pragma unroll
    for (int j = 0; j < 16; ++j) acc[j] = 0.f;

    const float4* sp = (const float4*)(src + lane * HID + k0);
    for (int kc = 0; kc < 16; ++kc) {
        float4 s4 = sp[kc];
        const float* wb = W + (size_t)(k0 + kc * 4) * ldw + cb;
        #pragma unroll
        for (int t = 0; t < 4; ++t) {
            float sv = (t == 0) ? s4.x : (t == 1) ? s4.y : (t == 2) ? s4.z : s4.w;
            const float4* wr = (const float4*)(wb + (size_t)t * ldw);
            #pragma unroll
            for (int j = 0; j < 4; ++j) {
                float4 w4 = wr[j];
                acc[4*j+0] = fmaf(sv, w4.x, acc[4*j+0]);
                acc[4*j+1] = fmaf(sv, w4.y, acc[4*j+1]);
                acc[4*j+2] = fmaf(sv, w4.z, acc[4*j+2]);
                acc[4*j+3] = fmaf(sv, w4.w, acc[4*j+3]);
            }
        }
    }

    __shared__ float red[16][16][64];
    #pragma unroll
    for (int j = 0; j < 16; ++j) red[wv][j][lane] = acc[j];
    __syncthreads();

    {
        const int j = tid >> 6, b = tid & 63;
        float s = 0.f;
        #pragma unroll
        for (int w = 0; w < 16; ++w) s += red[w][j][b];
        out[(c0 + j) * 64 + b] = s + bias[cb + j];
    }
}

// ---------------------------------------------------------------------------
// Kernel 2a: TWO-PHASE chunked attention partials with NON-TEMPORAL k/v
// loads (R7 kernel, unchanged). Block (c,b,h): 16 groups x 16 lanes.
// ---------------------------------------------------------------------------
__global__ __launch_bounds__(256) void attn_part_kernel(
    const float* __restrict__ proj, const float* __restrict__ k_cache,
    const float* __restrict__ v_cache, const int* __restrict__ seqlens,
    float* __restrict__ part)
{
    const int idx = blockIdx.x;
    const int c  = idx >> 10;          // chunk slowest: early blocks all valid
    const int bh = idx & 1023;
    const int b  = bh >> 4;
    const int h  = bh & 15;
    const int L  = seqlens[b];
    const int s0 = c << 8;
    if (s0 > L) return;

    const int tid = threadIdx.x;
    const int grp = tid >> 4;
    const int gl  = tid & 15;
    const bool has_new = (L < s0 + CHUNK);

    __shared__ float lq[64], lk[64], lv[64];
    __shared__ float sm_m[16], sm_l[16];
    __shared__ float sm_o[16][64];

    if (tid < 64) {                    // wave 0: q
        lq[tid] = proj[(h * 192 + tid) * 64 + b];
    } else if (tid < 128) {            // wave 1: normalized + fp16-rounded new k
        if (has_new) {
            int d = tid - 64;
            float kr = proj[(h * 192 + 64 + d) * 64 + b];
            float ss = kr * kr;
            #pragma unroll
            for (int m = 1; m < 64; m <<= 1) ss += __shfl_xor(ss, m);
            float kn = kr / sqrtf(ss);
            lk[d] = __half2float(__float2half_rn(kn));
        }
    } else if (tid < 192) {            // wave 2: new v
        if (has_new) {
            int d = tid - 128;
            lv[d] = proj[(h * 192 + 128 + d) * 64 + b];
        }
    }
    __syncthreads();

    const float4 q4 = ((const float4*)lq)[gl];
    const size_t base0 = (((size_t)b * MAXS) * NHEAD + h) * HD;

    float sc[16];
    float m, l;
    float4 o = make_float4(0.f, 0.f, 0.f, 0.f);

    if (!has_new) {
        // ---- Phase 1: K stream (nt), 16 independent score computations ----
        #pragma unroll
        for (int t = 0; t < 16; ++t) {
            const int s = s0 + grp + t * 16;
            float4 k4 = ntload4(k_cache + base0 + (size_t)s * (NHEAD * HD) + gl * 4);
            float d = fmaf(k4.x, q4.x, fmaf(k4.y, q4.y, fmaf(k4.z, q4.z, k4.w * q4.w)));
            d += __shfl_xor(d, 1); d += __shfl_xor(d, 2);
            d += __shfl_xor(d, 4); d += __shfl_xor(d, 8);
            sc[t] = d;
        }
        // ---- in-register softmax over the 16 scores ----
        m = sc[0];
        #pragma unroll
        for (int t = 1; t < 16; ++t) m = fmaxf(m, sc[t]);
        l = 0.f;
        #pragma unroll
        for (int t = 0; t < 16; ++t) { float p = __expf(sc[t] - m); sc[t] = p; l += p; }
        // ---- Phase 2: V stream (nt), independent accumulation ----
        #pragma unroll
        for (int t = 0; t < 16; ++t) {
            const int s = s0 + grp + t * 16;
            float4 v4 = ntload4(v_cache + base0 + (size_t)s * (NHEAD * HD) + gl * 4);
            o.x = fmaf(sc[t], v4.x, o.x);
            o.y = fmaf(sc[t], v4.y, o.y);
            o.z = fmaf(sc[t], v4.z, o.z);
            o.w = fmaf(sc[t], v4.w, o.w);
        }
    } else {
        // tail chunk: predicated, compile-time trip count
        #pragma unroll
        for (int t = 0; t < 16; ++t) {
            const int s = s0 + grp + t * 16;
            float4 k4 = make_float4(0.f, 0.f, 0.f, 0.f);
            if (s < L)       k4 = ntload4(k_cache + base0 + (size_t)s * (NHEAD * HD) + gl * 4);
            else if (s == L) k4 = ((const float4*)lk)[gl];
            float d = fmaf(k4.x, q4.x, fmaf(k4.y, q4.y, fmaf(k4.z, q4.z, k4.w * q4.w)));
            d += __shfl_xor(d, 1); d += __shfl_xor(d, 2);
            d += __shfl_xor(d, 4); d += __shfl_xor(d, 8);
            sc[t] = (s <= L) ? d : -INFINITY;
        }
        m = sc[0];
        #pragma unroll
        for (int t = 1; t < 16; ++t) m = fmaxf(m, sc[t]);
        // NaN guard: group entirely past L -> m = -inf; subtract 0 so
        // exp(-inf - 0) = 0, l = 0 (merge weight exp(-inf - M) = 0).
        const float mm = (m == -INFINITY) ? 0.f : m;
        l = 0.f;
        #pragma unroll
        for (int t = 0; t < 16; ++t) { float p = __expf(sc[t] - mm); sc[t] = p; l += p; }
        #pragma unroll
        for (int t = 0; t < 16; ++t) {
            const int s = s0 + grp + t * 16;
            float4 v4 = make_float4(0.f, 0.f, 0.f, 0.f);
            if (s < L)       v4 = ntload4(v_cache + base0 + (size_t)s * (NHEAD * HD) + gl * 4);
            else if (s == L) v4 = ((const float4*)lv)[gl];
            o.x = fmaf(sc[t], v4.x, o.x);
            o.y = fmaf(sc[t], v4.y, o.y);
            o.z = fmaf(sc[t], v4.z, o.z);
            o.w = fmaf(sc[t], v4.w, o.w);
        }
    }

    // ---- merge the 16 group-partials ----
    if (gl == 0) { sm_m[grp] = m; sm_l[grp] = l; }
    ((float4*)sm_o[grp])[gl] = o;
    __syncthreads();

    if (tid < 64) {
        float M = -INFINITY;
        #pragma unroll
        for (int g = 0; g < 16; ++g) M = fmaxf(M, sm_m[g]);
        float li = 0.f, oi = 0.f;
        #pragma unroll
        for (int g = 0; g < 16; ++g) {
            float w = __expf(sm_m[g] - M);   // empty group: exp(-inf - M) = 0
            li += w * sm_l[g];
            oi += w * sm_o[g][tid];
        }
        float* pb = part + (size_t)(c * 1024 + bh) * PS;
        pb[tid] = oi;
        if (tid == 0) { pb[64] = M; pb[65] = li; }
    }
}

// ---------------------------------------------------------------------------
// Kernel 2b: merge <=8 chunk partials per (b,h). 1024 blocks x 64 threads.
// ---------------------------------------------------------------------------
__global__ __launch_bounds__(64) void attn_merge_kernel(
    const float* __restrict__ part, const int* __restrict__ seqlens,
    float* __restrict__ attn_out /* [1024][64] col-major */)
{
    const int bh = blockIdx.x;
    const int b  = bh >> 4;
    const int h  = bh & 15;
    const int d  = threadIdx.x;
    const int nch = (seqlens[b] >> 8) + 1;

    float M = -INFINITY, l = 0.f, o = 0.f;
    for (int c = 0; c < nch; ++c) {
        const float* pb = part + (size_t)(c * 1024 + bh) * PS;
        float mc = pb[64], lc = pb[65];
        float Mn = fmaxf(M, mc);
        float f = __expf(M - Mn);
        float w = __expf(mc - Mn);
        o = o * f + w * pb[d];
        l = l * f + w * lc;
        M = Mn;
    }
    attn_out[(h * 64 + d) * 64 + b] = o / l;
}

// ---------------------------------------------------------------------------
// Kernel 3: postx = attn @ Wo + bo (unchanged)
// ---------------------------------------------------------------------------
__global__ __launch_bounds__(1024) void wo_kernel(
    const float* __restrict__ attn_s, const float* __restrict__ Wo,
    const float* __restrict__ bo, float* __restrict__ postx /* [1024][64] */)
{
    const int tid  = threadIdx.x;
    const int wv   = __builtin_amdgcn_readfirstlane(tid >> 6);
    const int lane = tid & 63;
    const int c0   = blockIdx.x * 8;
    const int k0   = wv * 64;

    float acc[8];
    #pragma unroll
    for (int j = 0; j < 8; ++j) acc[j] = 0.f;

    for (int k = 0; k < 64; ++k) {
        float sv = attn_s[(k0 + k) * 64 + lane];
        const float4* wr = (const float4*)(Wo + (size_t)(k0 + k) * 1024 + c0);
        float4 w0 = wr[0], w1 = wr[1];
        acc[0] = fmaf(sv, w0.x, acc[0]); acc[1] = fmaf(sv, w0.y, acc[1]);
        acc[2] = fmaf(sv, w0.z, acc[2]); acc[3] = fmaf(sv, w0.w, acc[3]);
        acc[4] = fmaf(sv, w1.x, acc[4]); acc[5] = fmaf(sv, w1.y, acc[5]);
        acc[6] = fmaf(sv, w1.z, acc[6]); acc[7] = fmaf(sv, w1.w, acc[7]);
    }

    __shared__ float red[16][8][64];
    #pragma unroll
    for (int j = 0; j < 8; ++j) red[wv][j][lane] = acc[j];
    __syncthreads();

    if (tid < 512) {
        const int j = tid >> 6, b = tid & 63;
        float s = 0.f;
        #pragma unroll
        for (int w = 0; w < 16; ++w) s += red[w][j][b];
        postx[(c0 + j) * 64 + b] = s + bo[c0 + j];
    }
}

// ---------------------------------------------------------------------------
// Kernel 4: dual LayerNorm (unchanged)
// ---------------------------------------------------------------------------
__global__ __launch_bounds__(256) void ln_kernel(
    const float* __restrict__ seq, const float* __restrict__ cand_s,
    const float* __restrict__ postx, const float* __restrict__ gamma,
    const float* __restrict__ beta, float* __restrict__ out)
{
    const int b   = blockIdx.x;
    const int tid = threadIdx.x;
    float x1[4], x2[4];
    float s1 = 0.f, q1 = 0.f, s2 = 0.f, q2 = 0.f;

    #pragma unroll
    for (int i = 0; i < 4; ++i) {
        int c = tid + i * 256;
        float px = postx[c * 64 + b];
        float sv = seq[b * HID + c];
        float cd = cand_s[c * 64 + b];
        float a = sv + px, d = px + cd;
        x1[i] = a; x2[i] = d;
        s1 += a; q1 += a * a; s2 += d; q2 += d * d;
    }
    #pragma unroll
    for (int m = 1; m < 64; m <<= 1) {
        s1 += __shfl_xor(s1, m); q1 += __shfl_xor(q1, m);
        s2 += __shfl_xor(s2, m); q2 += __shfl_xor(q2, m);
    }
    __shared__ float rsm[4][4];
    const int wv = tid >> 6, lane = tid & 63;
    if (lane == 0) { rsm[wv][0] = s1; rsm[wv][1] = q1; rsm[wv][2] = s2; rsm[wv][3] = q2; }
    __syncthreads();

    float S1 = rsm[0][0] + rsm[1][0] + rsm[2][0] + rsm[3][0];
    float Q1 = rsm[0][1] + rsm[1][1] + rsm[2][1] + rsm[3][1];
    float S2 = rsm[0][2] + rsm[1][2] + rsm[2][2] + rsm[3][2];
    float Q2 = rsm[0][3] + rsm[1][3] + rsm[2][3] + rsm[3][3];

    const float inv = 1.f / 1024.f;
    float mu1 = S1 * inv, v1 = Q1 * inv - mu1 * mu1;
    float mu2 = S2 * inv, v2 = Q2 * inv - mu2 * mu2;
    float r1 = rsqrtf(v1 + 1e-5f);
    float r2 = rsqrtf(v2 + 1e-5f);

    #pragma unroll
    for (int i = 0; i < 4; ++i) {
        int c = tid + i * 256;
        float g = gamma[c], be = beta[c];
        out[b * HID + c]            = (x1[i] - mu1) * r1 * g + be;   // seq_out
        out[NB * HID + b * HID + c] = (x2[i] - mu2) * r2 * g + be;   // candidate_out
    }
}

// ---------------------------------------------------------------------------
extern "C" void kernel_launch(void* const* d_in, const int* in_sizes, int n_in,
                              void* d_out, int out_size, void* d_ws, size_t ws_size,
                              hipStream_t stream) {
    const float* seq      = (const float*)d_in[0];
    const float* cand     = (const float*)d_in[1];
    const float* k_cache  = (const float*)d_in[2];
    const float* v_cache  = (const float*)d_in[3];
    const int*   seqlens  = (const int*)  d_in[4];
    const float* Wqkv     = (const float*)d_in[5];
    const float* bqkv     = (const float*)d_in[6];
    const float* Wc       = (const float*)d_in[7];
    const float* bcv      = (const float*)d_in[8];
    const float* Wo       = (const float*)d_in[9];
    const float* bo       = (const float*)d_in[10];
    const float* gamma    = (const float*)d_in[11];
    const float* beta     = (const float*)d_in[12];
    float* out = (float*)d_out;

    float* ws    = (float*)d_ws;
    float* proj  = ws;                         // [4096][64] = 262144 f
    float* attn  = proj  + 4096 * 64;          // [1024][64] =  65536 f
    float* postx = attn  + 1024 * 64;          // [1024][64] =  65536 f
    float* part  = postx + 1024 * 64;          // [8*1024][PS] = 557056 f

    proj_kernel      <<<256, 1024, 0, stream>>>(seq, cand, Wqkv, bqkv, Wc, bcv, proj);
    attn_part_kernel <<<NCH * 1024, 256, 0, stream>>>(proj, k_cache, v_cache, seqlens, part);
    attn_merge_kernel<<<NB * NHEAD, 64, 0, stream>>>(part, seqlens, attn);
    wo_kernel        <<<128, 1024, 0, stream>>>(attn, Wo, bo, postx);
    ln_kernel        <<<NB, 256, 0, stream>>>(seq, proj + 3072 * 64, postx, gamma, beta, out);
}